// Round 6
// baseline (264.502 us; speedup 1.0000x reference)
//
#include <hip/hip_runtime.h>
#include <hip/hip_cooperative_groups.h>

#define BB 8
#define LL 2048
#define CC 64
#define NCH 32
#define ST 68   // LDS stride (floats): 16B-aligned strips, conflict-managed

typedef float f32x4 __attribute__((ext_vector_type(4)));

static __device__ __forceinline__ f32x4 ffma4(f32x4 a, f32x4 b, f32x4 c) {
  return __builtin_elementwise_fma(a, b, c);
}
static __device__ __forceinline__ f32x4 bc4(float x) { return (f32x4){x, x, x, x}; }

// ===================== fused cooperative kernel =====================
// grid = 256 blocks (one per (s,c) chunk), 256 threads (4 waves x 16 rows).
// Stage A: stage KcT/VcT; partials PA=Vc^T Kc, PK=Kc^T Kc -> pref.
// Stage B: grid-wide exclusive prefix over chunks (in-place on pref).
// Stage C: 7-GEMM chunk expansion -> per-token u_t, w_t, nu_t.
// Stage D: blocks 0..7: per-stream prefix of (u,w,nu) -> out.
__global__ __launch_bounds__(256, 1) void kfused(const float* __restrict__ k,
                                                 const float* __restrict__ v,
                                                 float* __restrict__ pref,
                                                 float* __restrict__ nuw,
                                                 float* __restrict__ uw,
                                                 float* __restrict__ ww,
                                                 float* __restrict__ out) {
  __shared__ float B1[64 * ST];   // KcT
  __shared__ float B2[64 * ST];   // VcT
  __shared__ float B3[64 * ST];   // A0T -> K0 -> P^T -> Y^T
  __shared__ float sred[12];
  int s = blockIdx.x >> 5, c = blockIdx.x & 31;
  int tid = threadIdx.x, l = tid & 63, q = tid >> 6;
  int tq = q * 16;
  int tok0 = s * LL + c * CC;
  const float* kb = k + (size_t)tok0 * 64;
  const float* vb = v + (size_t)tok0 * 64;

  // ---- stage KcT / VcT (lane l reads row l, cols [tq,tq+16))
  #pragma unroll
  for (int e = 0; e < 4; ++e) {
    f32x4 kk = *(const f32x4*)(kb + l * 64 + tq + 4 * e);
    f32x4 vv = *(const f32x4*)(vb + l * 64 + tq + 4 * e);
    #pragma unroll
    for (int u = 0; u < 4; ++u) {
      int m = tq + 4 * e + u;
      B1[m * ST + l] = kk[u];
      B2[m * ST + l] = vv[u];
    }
  }
  __syncthreads();

  // ---- stage A: PA[i=l][j-strip] = sum_t VcT[t][l]*KcT[t][j]; PK likewise
  {
    f32x4 pa[4] = {}, pk[4] = {};
    #pragma unroll 4
    for (int t = 0; t < 64; ++t) {
      float vtl = B2[t * ST + l];
      float ktl = B1[t * ST + l];
      #pragma unroll
      for (int e = 0; e < 4; ++e) {
        f32x4 sk = *(const f32x4*)&B1[t * ST + tq + 4 * e];
        pa[e] = ffma4(bc4(vtl), sk, pa[e]);
        pk[e] = ffma4(bc4(ktl), sk, pk[e]);
      }
    }
    float* dst = pref + (size_t)(s * NCH + c) * 8192;
    #pragma unroll
    for (int e = 0; e < 4; ++e) {
      *(f32x4*)(dst + l * 64 + tq + 4 * e) = pa[e];
      *(f32x4*)(dst + 4096 + l * 64 + tq + 4 * e) = pk[e];
    }
  }
  __threadfence();
  cooperative_groups::this_grid().sync();

  // ---- stage B: exclusive prefix over 32 chunks (1 element/thread)
  {
    int gid = blockIdx.x * 256 + tid;
    int s2 = gid >> 13, e2 = gid & 8191;
    float* base = pref + (size_t)s2 * NCH * 8192 + e2;
    float x[16], y[16];
    #pragma unroll
    for (int u = 0; u < 16; ++u) x[u] = base[(size_t)u * 8192];
    #pragma unroll
    for (int u = 0; u < 16; ++u) y[u] = base[(size_t)(16 + u) * 8192];
    float acc = 0.f;
    #pragma unroll
    for (int u = 0; u < 16; ++u) { float t0 = x[u]; base[(size_t)u * 8192] = acc; acc += t0; }
    #pragma unroll
    for (int u = 0; u < 16; ++u) { float t0 = y[u]; base[(size_t)(16 + u) * 8192] = acc; acc += t0; }
  }
  __threadfence();
  cooperative_groups::this_grid().sync();

  // ---- stage C
  f32x4 X4[4] = {}, Y4[4] = {}, M4[4] = {}, N4[4] = {}, G4[4] = {}, Z4[4] = {};
  const float* gA0 = pref + (size_t)(s * NCH + c) * 8192;
  const float* gK0 = gA0 + 4096;
  // stage A0T into B3
  #pragma unroll
  for (int e = 0; e < 4; ++e) {
    f32x4 aa = *(const f32x4*)(gA0 + l * 64 + tq + 4 * e);
    #pragma unroll
    for (int u = 0; u < 4; ++u) B3[(tq + 4 * e + u) * ST + l] = aa[u];
  }
  __syncthreads();
  // phase 1a: X=Kc A0^T, M=Kc Kc^T, N=Vc Vc^T, G=Vc A0
  #pragma unroll 2
  for (int m = 0; m < 64; ++m) {
    float a0t = B3[m * ST + l];     // A0[l][m]
    float a0r = B3[l * ST + m];     // A0[m][l] (8-way, cheap)
    float kctl = B1[m * ST + l];    // Kc[l][m]
    float vctl = B2[m * ST + l];    // Vc[l][m]
    #pragma unroll
    for (int e = 0; e < 4; ++e) {
      f32x4 kcu = *(const f32x4*)&B1[m * ST + tq + 4 * e];
      f32x4 vcu = *(const f32x4*)&B2[m * ST + tq + 4 * e];
      X4[e] = ffma4(kcu, bc4(a0t), X4[e]);
      M4[e] = ffma4(kcu, bc4(kctl), M4[e]);
      N4[e] = ffma4(vcu, bc4(vctl), N4[e]);
      G4[e] = ffma4(vcu, bc4(a0r), G4[e]);
    }
  }
  __syncthreads();
  // stage K0 into B3 (K0 symmetric -> transposed staging == K0)
  #pragma unroll
  for (int e = 0; e < 4; ++e) {
    f32x4 kk0 = *(const f32x4*)(gK0 + l * 64 + tq + 4 * e);
    #pragma unroll
    for (int u = 0; u < 4; ++u) B3[(tq + 4 * e + u) * ST + l] = kk0[u];
  }
  __syncthreads();
  // phase 1b: Y = Kc K0
  #pragma unroll 4
  for (int m = 0; m < 64; ++m) {
    float k0r = B3[m * ST + l];     // K0[m][l]
    #pragma unroll
    for (int e = 0; e < 4; ++e) {
      f32x4 kcu = *(const f32x4*)&B1[m * ST + tq + 4 * e];
      Y4[e] = ffma4(kcu, bc4(k0r), Y4[e]);
    }
  }
  __syncthreads();
  // P^T into B3: P[t,i]=M[t,i]*(i<t)
  #pragma unroll
  for (int r = 0; r < 16; ++r) {
    int t = tq + r;
    B3[l * ST + t] = (l < t) ? M4[r >> 2][r & 3] : 0.f;
  }
  __syncthreads();
  // phase 2: X += P Vc, Y += P Kc
  #pragma unroll 2
  for (int i = 0; i < 64; ++i) {
    float vcl = B2[l * ST + i];     // Vc[i][l] (8-way)
    float kcl = B1[l * ST + i];     // Kc[i][l] (8-way)
    #pragma unroll
    for (int e = 0; e < 4; ++e) {
      f32x4 pu = *(const f32x4*)&B3[i * ST + tq + 4 * e];
      X4[e] = ffma4(pu, bc4(vcl), X4[e]);
      Y4[e] = ffma4(pu, bc4(kcl), Y4[e]);
    }
  }
  __syncthreads();
  // Y^T into B3
  #pragma unroll
  for (int r = 0; r < 16; ++r) B3[l * ST + tq + r] = Y4[r >> 2][r & 3];
  __syncthreads();
  // phase 3: Z[t,l] = sum_m Y[t,m] Kc[l,m]
  #pragma unroll 4
  for (int m = 0; m < 64; ++m) {
    float kclm = B1[m * ST + l];    // Kc[l][m]
    #pragma unroll
    for (int e = 0; e < 4; ++e) {
      f32x4 yu = *(const f32x4*)&B3[m * ST + tq + 4 * e];
      Z4[e] = ffma4(yu, bc4(kclm), Z4[e]);
    }
  }
  // epilogue: kappa/nu from M/N diagonals; dual butterfly per row
  {
    float usel = 0.f, wsel = 0.f, nsel = 0.f;
    #pragma unroll
    for (int r = 0; r < 16; ++r) {
      int t = tq + r;
      float ka = __shfl(M4[r >> 2][r & 3], t, 64);
      float nv = __shfl(N4[r >> 2][r & 3], t, 64);
      float vtl = B2[l * ST + t];   // Vc[t][l]
      float ktl = B1[l * ST + t];   // Kc[t][l]
      float xr = X4[r >> 2][r & 3];
      float yr = Y4[r >> 2][r & 3];
      float gr = G4[r >> 2][r & 3];
      float nr = N4[r >> 2][r & 3];
      float zr = Z4[r >> 2][r & 3];
      float zn = (l < t) ? zr * nr : 0.f;
      float ap = vtl * xr;
      float up = 2.f * (gr * yr + zn) + xr * xr + 2.f * ka * ap + nv * (ktl * yr);
      #pragma unroll
      for (int mm = 1; mm < 64; mm <<= 1) {
        up += __shfl_xor(up, mm, 64);
        ap += __shfl_xor(ap, mm, 64);
      }
      float ut = up + ka * ka * nv;
      float wt = fmaf(2.f, ap, ka * nv);
      bool sel = (l == r);
      usel = sel ? ut : usel;
      wsel = sel ? wt : wsel;
      nsel = sel ? nv : nsel;
    }
    if (l < 16) {
      uw[tok0 + tq + l] = usel;
      ww[tok0 + tq + l] = wsel;
      nuw[tok0 + tq + l] = nsel;
    }
  }
  __threadfence();
  cooperative_groups::this_grid().sync();

  // ---- stage D: per-stream prefixes -> out (blocks 0..7 only)
  if (blockIdx.x < BB) {
    int sD = blockIdx.x;
    int wv = q;
    const float* us = uw + sD * LL;
    const float* wsp = ww + sD * LL;
    const float* ns = nuw + sD * LL;
    float pu[8], pw[8], pn[8];
    int base = tid * 8;
    {
      float ru = 0, rw = 0, rn = 0;
      #pragma unroll
      for (int e = 0; e < 8; ++e) {
        ru += us[base + e]; pu[e] = ru;
        rw += wsp[base + e]; pw[e] = rw;
        rn += ns[base + e]; pn[e] = rn;
      }
    }
    float tu = pu[7], tw = pw[7], tn = pn[7];
    float iu = tu, iw = tw, in_ = tn;
    #pragma unroll
    for (int off = 1; off < 64; off <<= 1) {
      float a = __shfl_up(iu, off, 64);
      float b = __shfl_up(iw, off, 64);
      float c2 = __shfl_up(in_, off, 64);
      if (l >= off) { iu += a; iw += b; in_ += c2; }
    }
    if (l == 63) { sred[wv] = iu; sred[4 + wv] = iw; sred[8 + wv] = in_; }
    __syncthreads();
    float bu = 0, bw = 0, bn = 0;
    for (int i2 = 0; i2 < wv; ++i2) { bu += sred[i2]; bw += sred[4 + i2]; bn += sred[8 + i2]; }
    float eu = bu + iu - tu, ew = bw + iw - tw, en = bn + in_ - tn;
    float* os = out + sD * LL;
    #pragma unroll
    for (int e = 0; e < 8; ++e) {
      int t = base + e;
      float inv = 1.0f / (float)(t + 1);
      float U = eu + pu[e], W = ew + pw[e], S = en + pn[e];
      os[t] = inv * (0.5f * S + inv * fmaf(0.5f * inv, U, -W));
    }
  }
}

// ===================== fallback path (R5, known-good) =====================
__global__ __launch_bounds__(256) void fb_k1(const float* __restrict__ k,
                                             const float* __restrict__ v,
                                             float* __restrict__ pref_all,
                                             float* __restrict__ kap,
                                             float* __restrict__ nu) {
  int s = blockIdx.x / NCH, c = blockIdx.x % NCH;
  int tid = threadIdx.x;
  int lane = tid & 63, w = tid >> 6;
  int j0 = __builtin_amdgcn_readfirstlane(w * 16);
  int tok0 = s * LL + c * CC;
  const float* kb = k + (size_t)tok0 * 64;
  const float* vb = v + (size_t)tok0 * 64;
  f32x4 accA[4] = {}, accK[4] = {};
  for (int t = 0; t < CC; t += 2) {
    float vl0 = vb[t * 64 + lane], vl1 = vb[(t + 1) * 64 + lane];
    float kl0 = kb[t * 64 + lane], kl1 = kb[(t + 1) * 64 + lane];
    f32x4 s0[4], s1[4];
    #pragma unroll
    for (int e = 0; e < 4; ++e) {
      s0[e] = *(const f32x4*)(kb + t * 64 + j0 + 4 * e);
      s1[e] = *(const f32x4*)(kb + (t + 1) * 64 + j0 + 4 * e);
    }
    #pragma unroll
    for (int e = 0; e < 4; ++e) {
      accA[e] = ffma4(bc4(vl0), s0[e], accA[e]);
      accK[e] = ffma4(bc4(kl0), s0[e], accK[e]);
      accA[e] = ffma4(bc4(vl1), s1[e], accA[e]);
      accK[e] = ffma4(bc4(kl1), s1[e], accK[e]);
    }
  }
  float* dst = pref_all + (size_t)(s * NCH + c) * 8192;
  #pragma unroll
  for (int e = 0; e < 4; ++e) {
    *(f32x4*)(dst + lane * 64 + j0 + 4 * e) = accA[e];
    *(f32x4*)(dst + 4096 + lane * 64 + j0 + 4 * e) = accK[e];
  }
  for (int t = w; t < CC; t += 4) {
    float kl = kb[t * 64 + lane];
    float vl = vb[t * 64 + lane];
    float pk = kl * kl, pv = vl * vl;
    #pragma unroll
    for (int m = 1; m < 64; m <<= 1) {
      pk += __shfl_xor(pk, m, 64);
      pv += __shfl_xor(pv, m, 64);
    }
    if (lane == 0) { kap[tok0 + t] = pk; nu[tok0 + t] = pv; }
  }
}

__global__ __launch_bounds__(256) void fb_k2(float* __restrict__ pref_all) {
  int gid = blockIdx.x * 256 + threadIdx.x;
  int s = gid >> 13, e = gid & 8191;
  float* base = pref_all + (size_t)s * NCH * 8192 + e;
  float x[16], y[16];
  #pragma unroll
  for (int u = 0; u < 16; ++u) x[u] = base[(size_t)u * 8192];
  #pragma unroll
  for (int u = 0; u < 16; ++u) y[u] = base[(size_t)(16 + u) * 8192];
  float acc = 0.f;
  #pragma unroll
  for (int u = 0; u < 16; ++u) { float t = x[u]; base[(size_t)u * 8192] = acc; acc += t; }
  #pragma unroll
  for (int u = 0; u < 16; ++u) { float t = y[u]; base[(size_t)(16 + u) * 8192] = acc; acc += t; }
}

__global__ __launch_bounds__(256, 1) void fb_k3(const float* __restrict__ k,
                                                const float* __restrict__ v,
                                                const float* __restrict__ pref_all,
                                                const float* __restrict__ kap_all,
                                                const float* __restrict__ nu_all,
                                                float* __restrict__ uo,
                                                float* __restrict__ wo) {
  int s = blockIdx.x >> 5, c = blockIdx.x & 31;
  int tid = threadIdx.x;
  int l = tid & 63, q = tid >> 6;
  int tq = q * 16;
  __shared__ float sKcT[4096];
  __shared__ float sU1[4352];
  __shared__ float sU2[4352];
  int tok0 = s * LL + c * CC;
  const float* kb = k + (size_t)tok0 * 64;
  const float* vb = v + (size_t)tok0 * 64;
  const float* gA0 = pref_all + (size_t)(s * NCH + c) * 8192;
  const float* gK0 = gA0 + 4096;
  #pragma unroll
  for (int e = 0; e < 4; ++e) {
    f32x4 kk = *(const f32x4*)(kb + l * 64 + tq + 4 * e);
    f32x4 vv = *(const f32x4*)(vb + l * 64 + tq + 4 * e);
    f32x4 aa = *(const f32x4*)(gA0 + l * 64 + tq + 4 * e);
    #pragma unroll
    for (int u2 = 0; u2 < 4; ++u2) {
      int m = tq + 4 * e + u2;
      sKcT[m * 64 + l] = kk[u2];
      sU1[m * 64 + l] = vv[u2];
      sU2[m * 64 + l] = aa[u2];
    }
  }
  __syncthreads();
  f32x4 X4[4] = {}, Y4[4] = {}, M4[4] = {}, G4[4] = {}, N4[4] = {};
  #pragma unroll 2
  for (int m = 0; m < 64; ++m) {
    float a0t = sU2[m * 64 + l];
    float kctl = sKcT[m * 64 + l];
    float vctl = sU1[m * 64 + l];
    float a0r = gA0[m * 64 + l];
    float k0r = gK0[m * 64 + l];
    #pragma unroll
    for (int e = 0; e < 4; ++e) {
      f32x4 kcu = *(const f32x4*)&sKcT[m * 64 + tq + 4 * e];
      f32x4 vcu = *(const f32x4*)&sU1[m * 64 + tq + 4 * e];
      X4[e] = ffma4(kcu, bc4(a0t), X4[e]);
      Y4[e] = ffma4(kcu, bc4(k0r), Y4[e]);
      M4[e] = ffma4(kcu, bc4(kctl), M4[e]);
      G4[e] = ffma4(vcu, bc4(a0r), G4[e]);
      N4[e] = ffma4(vcu, bc4(vctl), N4[e]);
    }
  }
  __syncthreads();
  #pragma unroll
  for (int r = 0; r < 16; ++r) {
    int t = tq + r;
    sU2[l * 68 + t] = (l < t) ? M4[r >> 2][r & 3] : 0.f;
  }
  __syncthreads();
  #pragma unroll 2
  for (int i = 0; i < 64; ++i) {
    float vcl = vb[i * 64 + l];
    float kcl = kb[i * 64 + l];
    #pragma unroll
    for (int e = 0; e < 4; ++e) {
      f32x4 pu = *(const f32x4*)&sU2[i * 68 + tq + 4 * e];
      X4[e] = ffma4(pu, bc4(vcl), X4[e]);
      Y4[e] = ffma4(pu, bc4(kcl), Y4[e]);
    }
  }
  #pragma unroll
  for (int r = 0; r < 16; ++r) sU1[l * 68 + tq + r] = Y4[r >> 2][r & 3];
  __syncthreads();
  f32x4 Z4[4] = {};
  #pragma unroll 4
  for (int m = 0; m < 64; ++m) {
    float kt = sKcT[m * 64 + l];
    #pragma unroll
    for (int e = 0; e < 4; ++e) {
      f32x4 bu = *(const f32x4*)&sU1[m * 68 + tq + 4 * e];
      Z4[e] = ffma4(bu, bc4(kt), Z4[e]);
    }
  }
  float usel = 0.f, wsel = 0.f;
  #pragma unroll
  for (int r = 0; r < 16; ++r) {
    int t = tq + r;
    int gt = tok0 + t;
    float ka = kap_all[gt];
    float nv = nu_all[gt];
    float vtl = vb[t * 64 + l];
    float ktl = kb[t * 64 + l];
    float xr = X4[r >> 2][r & 3];
    float yr = Y4[r >> 2][r & 3];
    float gr = G4[r >> 2][r & 3];
    float nr = N4[r >> 2][r & 3];
    float zr = Z4[r >> 2][r & 3];
    float zn = (l < t) ? zr * nr : 0.f;
    float ap = vtl * xr;
    float up = 2.f * (gr * yr + zn) + xr * xr + 2.f * ka * ap + nv * (ktl * yr);
    #pragma unroll
    for (int mm = 1; mm < 64; mm <<= 1) {
      up += __shfl_xor(up, mm, 64);
      ap += __shfl_xor(ap, mm, 64);
    }
    float ut = up + ka * ka * nv;
    float wt = fmaf(2.f, ap, ka * nv);
    bool sel = (l == r);
    usel = sel ? ut : usel;
    wsel = sel ? wt : wsel;
  }
  if (l < 16) {
    uo[tok0 + tq + l] = usel;
    wo[tok0 + tq + l] = wsel;
  }
}

__global__ __launch_bounds__(256) void fb_k4(const float* __restrict__ u,
                                             const float* __restrict__ w,
                                             const float* __restrict__ nu,
                                             float* __restrict__ out) {
  int s = blockIdx.x;
  int tid = threadIdx.x, l = tid & 63, wv = tid >> 6;
  __shared__ float su[4], sw[4], sn[4];
  const float* us = u + s * LL;
  const float* wsp = w + s * LL;
  const float* ns = nu + s * LL;
  float pu[8], pw[8], pn[8];
  int base = tid * 8;
  {
    float ru = 0, rw = 0, rn = 0;
    #pragma unroll
    for (int e = 0; e < 8; ++e) {
      ru += us[base + e]; pu[e] = ru;
      rw += wsp[base + e]; pw[e] = rw;
      rn += ns[base + e]; pn[e] = rn;
    }
  }
  float tu = pu[7], tw = pw[7], tn = pn[7];
  float iu = tu, iw = tw, in_ = tn;
  #pragma unroll
  for (int off = 1; off < 64; off <<= 1) {
    float a = __shfl_up(iu, off, 64);
    float b = __shfl_up(iw, off, 64);
    float c2 = __shfl_up(in_, off, 64);
    if (l >= off) { iu += a; iw += b; in_ += c2; }
  }
  if (l == 63) { su[wv] = iu; sw[wv] = iw; sn[wv] = in_; }
  __syncthreads();
  float bu = 0, bw = 0, bn = 0;
  for (int i2 = 0; i2 < wv; ++i2) { bu += su[i2]; bw += sw[i2]; bn += sn[i2]; }
  float eu = bu + iu - tu, ew = bw + iw - tw, en = bn + in_ - tn;
  float* os = out + s * LL;
  #pragma unroll
  for (int e = 0; e < 8; ++e) {
    int t = base + e;
    float inv = 1.0f / (float)(t + 1);
    float U = eu + pu[e], W = ew + pw[e], S = en + pn[e];
    os[t] = inv * (0.5f * S + inv * fmaf(0.5f * inv, U, -W));
  }
}

extern "C" void kernel_launch(void* const* d_in, const int* in_sizes, int n_in,
                              void* d_out, int out_size, void* d_ws, size_t ws_size,
                              hipStream_t stream) {
  const float* k = (const float*)d_in[1];
  const float* v = (const float*)d_in[2];
  float* out = (float*)d_out;
  float* ws = (float*)d_ws;
  float* pref = ws;                                  // 8*32*8192
  float* nuB = ws + (size_t)BB * NCH * 8192;         // 16384
  float* uB = nuB + BB * LL;
  float* wB = uB + BB * LL;
  void* args[] = {(void*)&k, (void*)&v, (void*)&pref, (void*)&nuB,
                  (void*)&uB, (void*)&wB, (void*)&out};
  hipError_t err = hipLaunchCooperativeKernel((const void*)kfused, dim3(BB * NCH),
                                              dim3(256), args, 0, stream);
  if (err != hipSuccess) {
    // fallback: proven 4-kernel path (R5 layout: pref | kap | nu | u | w)
    float* kap = ws + (size_t)BB * NCH * 8192;
    float* nu = kap + BB * LL;
    float* uu = nu + BB * LL;
    float* ww2 = uu + BB * LL;
    hipLaunchKernelGGL(fb_k1, dim3(BB * NCH), dim3(256), 0, stream, k, v, pref, kap, nu);
    hipLaunchKernelGGL(fb_k2, dim3(BB * 8192 / 256), dim3(256), 0, stream, pref);
    hipLaunchKernelGGL(fb_k3, dim3(BB * NCH), dim3(256), 0, stream, k, v, pref, kap, nu, uu, ww2);
    hipLaunchKernelGGL(fb_k4, dim3(BB), dim3(256), 0, stream, uu, ww2, nu, out);
  }
}

// Round 7
// 49.310 us; speedup vs baseline: 5.3641x; 5.3641x over previous
//
#include <hip/hip_runtime.h>

#define BB 8
#define LL 2048
#define CC 64
#define NCH 32
#define ST4 68   // stride for the P^T/Y^T scratch (8-way write conflicts only)

typedef float f32x4 __attribute__((ext_vector_type(4)));

static __device__ __forceinline__ f32x4 ffma4(f32x4 a, f32x4 b, f32x4 c) {
  return __builtin_elementwise_fma(a, b, c);
}
static __device__ __forceinline__ f32x4 bc4(float x) { return (f32x4){x, x, x, x}; }

// ws layout (floats): pref[BB*NCH*8192] | kap[BB*LL] | nu[BB*LL] | u[BB*LL] | w[BB*LL]

// K1: grid 512. Block = (s, c, jh): partial sums PA=Vc^T Kc, PK=Kc^T Kc for
// j-columns [32jh, 32jh+32); kappa/nu for tokens [32jh, 32jh+32).
__global__ __launch_bounds__(256, 2) void k1_partial(const float* __restrict__ k,
                                                     const float* __restrict__ v,
                                                     float* __restrict__ pref_all,
                                                     float* __restrict__ kap,
                                                     float* __restrict__ nu) {
  int b = blockIdx.x;
  int s = b >> 6, rem = b & 63, c = rem >> 1, jh = rem & 1;
  int tid = threadIdx.x, lane = tid & 63, w = tid >> 6;
  int j0 = __builtin_amdgcn_readfirstlane(jh * 32 + w * 8);
  int tok0 = s * LL + c * CC;
  const float* kb = k + (size_t)tok0 * 64;
  const float* vb = v + (size_t)tok0 * 64;
  f32x4 accA[2] = {}, accK[2] = {};
  for (int t = 0; t < CC; t += 2) {
    float vl0 = vb[t * 64 + lane], vl1 = vb[(t + 1) * 64 + lane];
    float kl0 = kb[t * 64 + lane], kl1 = kb[(t + 1) * 64 + lane];
    f32x4 s0[2], s1[2];
    #pragma unroll
    for (int e = 0; e < 2; ++e) {
      s0[e] = *(const f32x4*)(kb + t * 64 + j0 + 4 * e);
      s1[e] = *(const f32x4*)(kb + (t + 1) * 64 + j0 + 4 * e);
    }
    #pragma unroll
    for (int e = 0; e < 2; ++e) {
      accA[e] = ffma4(bc4(vl0), s0[e], accA[e]);
      accK[e] = ffma4(bc4(kl0), s0[e], accK[e]);
      accA[e] = ffma4(bc4(vl1), s1[e], accA[e]);
      accK[e] = ffma4(bc4(kl1), s1[e], accK[e]);
    }
  }
  float* dst = pref_all + (size_t)(s * NCH + c) * 8192;
  #pragma unroll
  for (int e = 0; e < 2; ++e) {
    *(f32x4*)(dst + lane * 64 + j0 + 4 * e) = accA[e];
    *(f32x4*)(dst + 4096 + lane * 64 + j0 + 4 * e) = accK[e];
  }
  for (int t = jh * 32 + w; t < jh * 32 + 32; t += 4) {
    float kl = kb[t * 64 + lane];
    float vl = vb[t * 64 + lane];
    float pk = kl * kl, pv = vl * vl;
    #pragma unroll
    for (int m = 1; m < 64; m <<= 1) {
      pk += __shfl_xor(pk, m, 64);
      pv += __shfl_xor(pv, m, 64);
    }
    if (lane == 0) { kap[tok0 + t] = pk; nu[tok0 + t] = pv; }
  }
}

// K2: in-place exclusive prefix over 32 chunks; 16-deep batches with prefetch
__global__ __launch_bounds__(256) void k2_prefix(float* __restrict__ pref_all) {
  int gid = blockIdx.x * 256 + threadIdx.x;   // [0, BB*8192)
  int s = gid >> 13, e = gid & 8191;
  float* base = pref_all + (size_t)s * NCH * 8192 + e;
  float x[16], y[16];
  #pragma unroll
  for (int u = 0; u < 16; ++u) x[u] = base[(size_t)u * 8192];
  #pragma unroll
  for (int u = 0; u < 16; ++u) y[u] = base[(size_t)(16 + u) * 8192];
  float acc = 0.f;
  #pragma unroll
  for (int u = 0; u < 16; ++u) { float t = x[u]; base[(size_t)u * 8192] = acc; acc += t; }
  #pragma unroll
  for (int u = 0; u < 16; ++u) { float t = y[u]; base[(size_t)(16 + u) * 8192] = acc; acc += t; }
}

// K3: chunk expansion. grid 512: block = (s, c, row-half). 4 waves x 8 rows,
// lane = column. All contraction-loop operands from LDS in the conflict-free
// direction (uniform-row strips + per-lane-consecutive b32). K0 symmetric ->
// transposed staging free. G-term computed as G2 = Y A0^T in phase 3.
__global__ __launch_bounds__(256, 2) void k3_gemm(const float* __restrict__ k,
                                                  const float* __restrict__ v,
                                                  const float* __restrict__ pref_all,
                                                  const float* __restrict__ kap_all,
                                                  const float* __restrict__ nu_all,
                                                  float* __restrict__ uo,
                                                  float* __restrict__ wo) {
  __shared__ float B1[4096];       // KcT: B1[j*64+t] = Kc[t][j]
  __shared__ float B2[4096];       // VcT: B2[j*64+t] = Vc[t][j]
  __shared__ float B3[4096];       // A0T: B3[j*64+i] = A0[i][j]
  __shared__ float B4[64 * ST4];   // K0T -> P^T -> Y^T
  int b = blockIdx.x;
  int s = b >> 6, rem = b & 63, c = rem >> 1, rh = rem & 1;
  int rbase = rh * 32;
  int tid = threadIdx.x, l = tid & 63, q = tid >> 6;
  int tq = q * 16;              // staging column block
  int lr0 = rbase + q * 8;      // wave's global output-row base
  int lq = q * 8;               // wave's local row base in [0,32)
  int tok0 = s * LL + c * CC;
  const float* kb = k + (size_t)tok0 * 64;
  const float* vb = v + (size_t)tok0 * 64;
  const float* gA0 = pref_all + (size_t)(s * NCH + c) * 8192;
  const float* gK0 = gA0 + 4096;

  // stage all four operands (transposing; per-lane col writes, conflict-free)
  #pragma unroll
  for (int e = 0; e < 4; ++e) {
    f32x4 kk = *(const f32x4*)(kb + l * 64 + tq + 4 * e);
    f32x4 vv = *(const f32x4*)(vb + l * 64 + tq + 4 * e);
    f32x4 aa = *(const f32x4*)(gA0 + l * 64 + tq + 4 * e);
    f32x4 k0 = *(const f32x4*)(gK0 + l * 64 + tq + 4 * e);
    #pragma unroll
    for (int u = 0; u < 4; ++u) {
      int m = tq + 4 * e + u;
      B1[m * 64 + l] = kk[u];
      B2[m * 64 + l] = vv[u];
      B3[m * 64 + l] = aa[u];
      B4[m * ST4 + l] = k0[u];
    }
  }
  __syncthreads();

  f32x4 X[2] = {}, Y[2] = {}, M[2] = {}, N[2] = {}, Z[2] = {}, G2[2] = {};
  // phase 1: X=Kc A0^T, M=Kc Kc^T, Y=Kc K0, N=Vc Vc^T (all-LDS)
  #pragma unroll 2
  for (int m = 0; m < 64; ++m) {
    float a0t = B3[m * 64 + l];      // A0[l][m]
    float kctl = B1[m * 64 + l];     // Kc[l][m]
    float vctl = B2[m * 64 + l];     // Vc[l][m]
    float k0r = B4[m * ST4 + l];     // K0[l][m] == K0[m][l]
    #pragma unroll
    for (int e = 0; e < 2; ++e) {
      f32x4 kcu = *(const f32x4*)&B1[m * 64 + lr0 + 4 * e];
      f32x4 vcu = *(const f32x4*)&B2[m * 64 + lr0 + 4 * e];
      X[e] = ffma4(kcu, bc4(a0t), X[e]);
      M[e] = ffma4(kcu, bc4(kctl), M[e]);
      Y[e] = ffma4(kcu, bc4(k0r), Y[e]);
      N[e] = ffma4(vcu, bc4(vctl), N[e]);
    }
  }
  __syncthreads();
  // P^T into B4: PT[i=l][local t] = (l < t) ? M[t][l] : 0
  #pragma unroll
  for (int r = 0; r < 8; ++r) {
    int t = lr0 + r;
    B4[l * ST4 + lq + r] = (l < t) ? M[r >> 2][r & 3] : 0.f;
  }
  __syncthreads();
  // phase 2: X += P Vc, Y += P Kc (per-lane Vc/Kc rows from global, L1-warm)
  #pragma unroll 4
  for (int i = 0; i < 64; ++i) {
    float vcl = vb[i * 64 + l];
    float kcl = kb[i * 64 + l];
    #pragma unroll
    for (int e = 0; e < 2; ++e) {
      f32x4 pu = *(const f32x4*)&B4[i * ST4 + lq + 4 * e];
      X[e] = ffma4(pu, bc4(vcl), X[e]);
      Y[e] = ffma4(pu, bc4(kcl), Y[e]);
    }
  }
  __syncthreads();
  // Y^T into B4
  #pragma unroll
  for (int r = 0; r < 8; ++r)
    B4[l * ST4 + lq + r] = Y[r >> 2][r & 3];
  __syncthreads();
  // phase 3: Z[t][l] = sum_m Y[t][m] Kc[l][m];  G2[t][l] = sum_m Y[t][m] A0[l][m]
  #pragma unroll 2
  for (int m = 0; m < 64; ++m) {
    float kcll = B1[m * 64 + l];
    float a0ll = B3[m * 64 + l];
    #pragma unroll
    for (int e = 0; e < 2; ++e) {
      f32x4 yu = *(const f32x4*)&B4[m * ST4 + lq + 4 * e];
      Z[e] = ffma4(yu, bc4(kcll), Z[e]);
      G2[e] = ffma4(yu, bc4(a0ll), G2[e]);
    }
  }
  // epilogue: per-row butterfly reductions
  float usel = 0.f, wsel = 0.f;
  #pragma unroll
  for (int r = 0; r < 8; ++r) {
    int t = lr0 + r;
    int gt = tok0 + t;
    float ka = kap_all[gt];
    float nv = nu_all[gt];
    float vtl = vb[t * 64 + l];
    float ktl = kb[t * 64 + l];
    float xr = X[r >> 2][r & 3];
    float yr = Y[r >> 2][r & 3];
    float nr = N[r >> 2][r & 3];
    float zr = Z[r >> 2][r & 3];
    float g2 = G2[r >> 2][r & 3];
    float zn = (l < t) ? zr * nr : 0.f;
    float ap = vtl * xr;
    float up = 2.f * (vtl * g2 + zn) + xr * xr + 2.f * ka * ap + nv * (ktl * yr);
    #pragma unroll
    for (int mm = 1; mm < 64; mm <<= 1) {
      up += __shfl_xor(up, mm, 64);
      ap += __shfl_xor(ap, mm, 64);
    }
    float ut = up + ka * ka * nv;
    float wt = fmaf(2.f, ap, ka * nv);
    bool sel = (l == r);
    usel = sel ? ut : usel;
    wsel = sel ? wt : wsel;
  }
  if (l < 8) {
    uo[tok0 + lr0 + l] = usel;
    wo[tok0 + lr0 + l] = wsel;
  }
}

// K4: per-stream inclusive prefixes of u (->T), w (->F), nu (->S); emit out.
__global__ __launch_bounds__(256) void k4_out(const float* __restrict__ u,
                                              const float* __restrict__ w,
                                              const float* __restrict__ nu,
                                              float* __restrict__ out) {
  int s = blockIdx.x;
  int tid = threadIdx.x, l = tid & 63, wv = tid >> 6;
  __shared__ float su[4], sw[4], sn[4];
  const float* us = u + s * LL;
  const float* wsp = w + s * LL;
  const float* ns = nu + s * LL;
  float pu[8], pw[8], pn[8];
  int base = tid * 8;
  {
    float ru = 0, rw = 0, rn = 0;
    #pragma unroll
    for (int e = 0; e < 8; ++e) {
      ru += us[base + e]; pu[e] = ru;
      rw += wsp[base + e]; pw[e] = rw;
      rn += ns[base + e]; pn[e] = rn;
    }
  }
  float tu = pu[7], tw = pw[7], tn = pn[7];
  float iu = tu, iw = tw, in_ = tn;
  #pragma unroll
  for (int off = 1; off < 64; off <<= 1) {
    float a = __shfl_up(iu, off, 64);
    float b = __shfl_up(iw, off, 64);
    float c2 = __shfl_up(in_, off, 64);
    if (l >= off) { iu += a; iw += b; in_ += c2; }
  }
  if (l == 63) { su[wv] = iu; sw[wv] = iw; sn[wv] = in_; }
  __syncthreads();
  float bu = 0, bw = 0, bn = 0;
  for (int i2 = 0; i2 < wv; ++i2) { bu += su[i2]; bw += sw[i2]; bn += sn[i2]; }
  float eu = bu + iu - tu, ew = bw + iw - tw, en = bn + in_ - tn;
  float* os = out + s * LL;
  #pragma unroll
  for (int e = 0; e < 8; ++e) {
    int t = base + e;
    float inv = 1.0f / (float)(t + 1);
    float U = eu + pu[e], W = ew + pw[e], S = en + pn[e];
    os[t] = inv * (0.5f * S + inv * fmaf(0.5f * inv, U, -W));
  }
}

extern "C" void kernel_launch(void* const* d_in, const int* in_sizes, int n_in,
                              void* d_out, int out_size, void* d_ws, size_t ws_size,
                              hipStream_t stream) {
  const float* k = (const float*)d_in[1];
  const float* v = (const float*)d_in[2];
  float* out = (float*)d_out;
  float* ws = (float*)d_ws;
  float* pref = ws;
  float* kap = ws + (size_t)BB * NCH * 8192;
  float* nu  = kap + BB * LL;
  float* uu  = nu + BB * LL;
  float* ww  = uu + BB * LL;
  hipLaunchKernelGGL(k1_partial, dim3(BB * NCH * 2), dim3(256), 0, stream, k, v, pref, kap, nu);
  hipLaunchKernelGGL(k2_prefix, dim3(BB * 8192 / 256), dim3(256), 0, stream, pref);
  hipLaunchKernelGGL(k3_gemm, dim3(BB * NCH * 2), dim3(256), 0, stream, k, v, pref, kap, nu, uu, ww);
  hipLaunchKernelGGL(k4_out, dim3(BB), dim3(256), 0, stream, uu, ww, nu, out);
}

// Round 8
// 33.398 us; speedup vs baseline: 7.9197x; 1.4764x over previous
//
#include <hip/hip_runtime.h>

#define BB 8
#define LL 2048
#define CC 64
#define NCH 32
#define SB 72   // bf16 LDS row stride (144 B): 16B-aligned, 2-way banks

typedef float f32x4 __attribute__((ext_vector_type(4)));
typedef short bf8 __attribute__((ext_vector_type(8)));

static __device__ __forceinline__ f32x4 ffma4(f32x4 a, f32x4 b, f32x4 c) {
  return __builtin_elementwise_fma(a, b, c);
}
static __device__ __forceinline__ f32x4 bc4(float x) { return (f32x4){x, x, x, x}; }
static __device__ __forceinline__ unsigned short f2b(float f) {
  unsigned u = __builtin_bit_cast(unsigned, f);
  u += 0x7fff + ((u >> 16) & 1);   // RNE (no NaN in this data)
  return (unsigned short)(u >> 16);
}
static __device__ __forceinline__ float b2f(unsigned short h) {
  return __builtin_bit_cast(float, ((unsigned)h) << 16);
}
#define MFMA(A, B, C) __builtin_amdgcn_mfma_f32_16x16x32_bf16(A, B, C, 0, 0, 0)

// ws layout (floats): pref[BB*NCH*8192] | kap[BB*LL] | nu[BB*LL] | u[BB*LL] | w[BB*LL]

// K1 (proven R7): per-chunk partials PA=Vc^T Kc, PK=Kc^T Kc + kappa/nu.
__global__ __launch_bounds__(256, 2) void k1_partial(const float* __restrict__ k,
                                                     const float* __restrict__ v,
                                                     float* __restrict__ pref_all,
                                                     float* __restrict__ kap,
                                                     float* __restrict__ nu) {
  int b = blockIdx.x;
  int s = b >> 6, rem = b & 63, c = rem >> 1, jh = rem & 1;
  int tid = threadIdx.x, lane = tid & 63, w = tid >> 6;
  int j0 = __builtin_amdgcn_readfirstlane(jh * 32 + w * 8);
  int tok0 = s * LL + c * CC;
  const float* kb = k + (size_t)tok0 * 64;
  const float* vb = v + (size_t)tok0 * 64;
  f32x4 accA[2] = {}, accK[2] = {};
  for (int t = 0; t < CC; t += 2) {
    float vl0 = vb[t * 64 + lane], vl1 = vb[(t + 1) * 64 + lane];
    float kl0 = kb[t * 64 + lane], kl1 = kb[(t + 1) * 64 + lane];
    f32x4 s0[2], s1[2];
    #pragma unroll
    for (int e = 0; e < 2; ++e) {
      s0[e] = *(const f32x4*)(kb + t * 64 + j0 + 4 * e);
      s1[e] = *(const f32x4*)(kb + (t + 1) * 64 + j0 + 4 * e);
    }
    #pragma unroll
    for (int e = 0; e < 2; ++e) {
      accA[e] = ffma4(bc4(vl0), s0[e], accA[e]);
      accK[e] = ffma4(bc4(kl0), s0[e], accK[e]);
      accA[e] = ffma4(bc4(vl1), s1[e], accA[e]);
      accK[e] = ffma4(bc4(kl1), s1[e], accK[e]);
    }
  }
  float* dst = pref_all + (size_t)(s * NCH + c) * 8192;
  #pragma unroll
  for (int e = 0; e < 2; ++e) {
    *(f32x4*)(dst + lane * 64 + j0 + 4 * e) = accA[e];
    *(f32x4*)(dst + 4096 + lane * 64 + j0 + 4 * e) = accK[e];
  }
  for (int t = jh * 32 + w; t < jh * 32 + 32; t += 4) {
    float kl = kb[t * 64 + lane];
    float vl = vb[t * 64 + lane];
    float pk = kl * kl, pv = vl * vl;
    #pragma unroll
    for (int m = 1; m < 64; m <<= 1) {
      pk += __shfl_xor(pk, m, 64);
      pv += __shfl_xor(pv, m, 64);
    }
    if (lane == 0) { kap[tok0 + t] = pk; nu[tok0 + t] = pv; }
  }
}

// K2 (proven): in-place exclusive prefix over 32 chunks
__global__ __launch_bounds__(256) void k2_prefix(float* __restrict__ pref_all) {
  int gid = blockIdx.x * 256 + threadIdx.x;
  int s = gid >> 13, e = gid & 8191;
  float* base = pref_all + (size_t)s * NCH * 8192 + e;
  float x[16], y[16];
  #pragma unroll
  for (int u = 0; u < 16; ++u) x[u] = base[(size_t)u * 8192];
  #pragma unroll
  for (int u = 0; u < 16; ++u) y[u] = base[(size_t)(16 + u) * 8192];
  float acc = 0.f;
  #pragma unroll
  for (int u = 0; u < 16; ++u) { float t = x[u]; base[(size_t)u * 8192] = acc; acc += t; }
  #pragma unroll
  for (int u = 0; u < 16; ++u) { float t = y[u]; base[(size_t)(16 + u) * 8192] = acc; acc += t; }
}

// K3: MFMA chunk expansion. 1 block (512 thr, 8 waves) per chunk.
// Wave q: rows R0=16*(q&3), cols C0=32*(q>>2) (2 n-tiles) of every 64x64 GEMM.
// Round A: M=Kc Kc^T, N=Vc Vc^T, X=Kc A0^T, Y=Kc K0  -> P=tril(M,-1), diag k/n
// Round B: X+=P Vc (via VcT), Y+=P Kc (via KcT)       -> Y tile
// Round C: Z=Y Kc^T, G=Y A0^T -> epilogue row-dots -> u_t, w_t
__global__ __launch_bounds__(512, 1) void k3_mfma(const float* __restrict__ k,
                                                  const float* __restrict__ v,
                                                  const float* __restrict__ pref_all,
                                                  float* __restrict__ uo,
                                                  float* __restrict__ wo) {
  __shared__ unsigned short sKc[64 * SB], sVc[64 * SB], sA0[64 * SB],
                            sK0[64 * SB], sKcT[64 * SB], sVcT[64 * SB];
  __shared__ float sdK[64], sdN[64], comb[64][2][2];
  unsigned short* sP = sK0;    // K0 dead after round A (barrier-guarded)
  unsigned short* sY = sVcT;   // VcT dead after round B (barrier-guarded)
  int s = blockIdx.x >> 5, c = blockIdx.x & 31;
  int tid = threadIdx.x;
  int tok0 = s * LL + c * CC;
  const float* kb = k + (size_t)tok0 * 64;
  const float* vb = v + (size_t)tok0 * 64;
  const float* gA0 = pref_all + (size_t)(s * NCH + c) * 8192;
  const float* gK0 = gA0 + 4096;

  // ---- stage: fp32 -> bf16 tiles (rows) + transposed Kc/Vc
  {
    int r = tid >> 3, cb = (tid & 7) * 8;
    f32x4 ka_ = *(const f32x4*)(kb + r * 64 + cb);
    f32x4 kb_ = *(const f32x4*)(kb + r * 64 + cb + 4);
    f32x4 va_ = *(const f32x4*)(vb + r * 64 + cb);
    f32x4 vb_ = *(const f32x4*)(vb + r * 64 + cb + 4);
    f32x4 aa_ = *(const f32x4*)(gA0 + r * 64 + cb);
    f32x4 ab_ = *(const f32x4*)(gA0 + r * 64 + cb + 4);
    f32x4 qa_ = *(const f32x4*)(gK0 + r * 64 + cb);
    f32x4 qb_ = *(const f32x4*)(gK0 + r * 64 + cb + 4);
    bf8 wk, wv, wa, wq;
    #pragma unroll
    for (int u = 0; u < 4; ++u) {
      wk[u] = (short)f2b(ka_[u]); wk[4 + u] = (short)f2b(kb_[u]);
      wv[u] = (short)f2b(va_[u]); wv[4 + u] = (short)f2b(vb_[u]);
      wa[u] = (short)f2b(aa_[u]); wa[4 + u] = (short)f2b(ab_[u]);
      wq[u] = (short)f2b(qa_[u]); wq[4 + u] = (short)f2b(qb_[u]);
    }
    *(bf8*)&sKc[r * SB + cb] = wk;
    *(bf8*)&sVc[r * SB + cb] = wv;
    *(bf8*)&sA0[r * SB + cb] = wa;
    *(bf8*)&sK0[r * SB + cb] = wq;
    #pragma unroll
    for (int u = 0; u < 8; ++u) {
      sKcT[(cb + u) * SB + r] = (unsigned short)wk[u];
      sVcT[(cb + u) * SB + r] = (unsigned short)wv[u];
    }
  }
  __syncthreads();

  int l = tid & 63, q = tid >> 6;
  int R0 = (q & 3) * 16, C0 = (q >> 2) * 32, ch = q >> 2;
  int ar = R0 + (l & 15);
  int ko = (l >> 4) * 8;
#define LDA(T, ks) (*(const bf8*)&(T)[ar * SB + ko + (ks) * 32])
#define LDB(T, nt, ks) (*(const bf8*)&(T)[(C0 + 16 * (nt) + (l & 15)) * SB + ko + (ks) * 32])

  f32x4 X[2] = {}, Y[2] = {}, M[2] = {}, N[2] = {};
  #pragma unroll
  for (int ks = 0; ks < 2; ++ks) {
    bf8 aK = LDA(sKc, ks), aV = LDA(sVc, ks);
    #pragma unroll
    for (int nt = 0; nt < 2; ++nt) {
      M[nt] = MFMA(aK, LDB(sKc, nt, ks), M[nt]);
      N[nt] = MFMA(aV, LDB(sVc, nt, ks), N[nt]);
      X[nt] = MFMA(aK, LDB(sA0, nt, ks), X[nt]);
      Y[nt] = MFMA(aK, LDB(sK0, nt, ks), Y[nt]);
    }
  }
  __syncthreads();   // all round-A reads of sK0 done before P overwrites it
  #pragma unroll
  for (int nt = 0; nt < 2; ++nt)
    #pragma unroll
    for (int reg = 0; reg < 4; ++reg) {
      int row = R0 + (l >> 4) * 4 + reg;
      int col = C0 + 16 * nt + (l & 15);
      float m = M[nt][reg];
      sP[row * SB + col] = (col < row) ? f2b(m) : (unsigned short)0;
      if (col == row) { sdK[row] = m; sdN[row] = N[nt][reg]; }
    }
  __syncthreads();
  #pragma unroll
  for (int ks = 0; ks < 2; ++ks) {
    bf8 aP = LDA(sP, ks);
    #pragma unroll
    for (int nt = 0; nt < 2; ++nt) {
      X[nt] = MFMA(aP, LDB(sVcT, nt, ks), X[nt]);
      Y[nt] = MFMA(aP, LDB(sKcT, nt, ks), Y[nt]);
    }
  }
  __syncthreads();   // all round-B reads of sVcT done before Y overwrites it
  #pragma unroll
  for (int nt = 0; nt < 2; ++nt)
    #pragma unroll
    for (int reg = 0; reg < 4; ++reg) {
      int row = R0 + (l >> 4) * 4 + reg;
      int col = C0 + 16 * nt + (l & 15);
      sY[row * SB + col] = f2b(Y[nt][reg]);
    }
  __syncthreads();
  f32x4 Z[2] = {}, G[2] = {};
  #pragma unroll
  for (int ks = 0; ks < 2; ++ks) {
    bf8 aY = LDA(sY, ks);
    #pragma unroll
    for (int nt = 0; nt < 2; ++nt) {
      Z[nt] = MFMA(aY, LDB(sKc, nt, ks), Z[nt]);
      G[nt] = MFMA(aY, LDB(sA0, nt, ks), G[nt]);
    }
  }
  // ---- epilogue: per-row dots in D-layout (col=l&15, row=(l>>4)*4+reg)
  #pragma unroll
  for (int reg = 0; reg < 4; ++reg) {
    int row = R0 + (l >> 4) * 4 + reg;
    float ka = sdK[row], nv = sdN[row];
    float pu = 0.f, pw = 0.f;
    #pragma unroll
    for (int nt = 0; nt < 2; ++nt) {
      int col = C0 + 16 * nt + (l & 15);
      float x = X[nt][reg], y = Y[nt][reg], n = N[nt][reg];
      float z = Z[nt][reg], g = G[nt][reg];
      float vtl = b2f(sVc[row * SB + col]);
      float ktl = b2f(sKc[row * SB + col]);
      float zn = (col < row) ? z * n : 0.f;
      float vx = vtl * x;
      pu += 2.f * (vtl * g + zn) + x * x + 2.f * ka * vx + nv * (ktl * y);
      pw += vx;
    }
    #pragma unroll
    for (int mm = 1; mm < 16; mm <<= 1) {
      pu += __shfl_xor(pu, mm, 64);
      pw += __shfl_xor(pw, mm, 64);
    }
    if ((l & 15) == 0) { comb[row][ch][0] = pu; comb[row][ch][1] = pw; }
  }
  __syncthreads();
  if (tid < 64) {
    float ka = sdK[tid], nv = sdN[tid];
    float u = comb[tid][0][0] + comb[tid][1][0] + ka * ka * nv;
    float w = 2.f * (comb[tid][0][1] + comb[tid][1][1]) + ka * nv;
    uo[tok0 + tid] = u;
    wo[tok0 + tid] = w;
  }
#undef LDA
#undef LDB
}

// K4 (proven): per-stream inclusive prefixes of u, w, nu -> out.
__global__ __launch_bounds__(256) void k4_out(const float* __restrict__ u,
                                              const float* __restrict__ w,
                                              const float* __restrict__ nu,
                                              float* __restrict__ out) {
  int s = blockIdx.x;
  int tid = threadIdx.x, l = tid & 63, wv = tid >> 6;
  __shared__ float su[4], sw[4], sn[4];
  const float* us = u + s * LL;
  const float* wsp = w + s * LL;
  const float* ns = nu + s * LL;
  float pu[8], pw[8], pn[8];
  int base = tid * 8;
  {
    float ru = 0, rw = 0, rn = 0;
    #pragma unroll
    for (int e = 0; e < 8; ++e) {
      ru += us[base + e]; pu[e] = ru;
      rw += wsp[base + e]; pw[e] = rw;
      rn += ns[base + e]; pn[e] = rn;
    }
  }
  float tu = pu[7], tw = pw[7], tn = pn[7];
  float iu = tu, iw = tw, in_ = tn;
  #pragma unroll
  for (int off = 1; off < 64; off <<= 1) {
    float a = __shfl_up(iu, off, 64);
    float b = __shfl_up(iw, off, 64);
    float c2 = __shfl_up(in_, off, 64);
    if (l >= off) { iu += a; iw += b; in_ += c2; }
  }
  if (l == 63) { su[wv] = iu; sw[wv] = iw; sn[wv] = in_; }
  __syncthreads();
  float bu = 0, bw = 0, bn = 0;
  for (int i2 = 0; i2 < wv; ++i2) { bu += su[i2]; bw += sw[i2]; bn += sn[i2]; }
  float eu = bu + iu - tu, ew = bw + iw - tw, en = bn + in_ - tn;
  float* os = out + s * LL;
  #pragma unroll
  for (int e = 0; e < 8; ++e) {
    int t = base + e;
    float inv = 1.0f / (float)(t + 1);
    float U = eu + pu[e], W = ew + pw[e], S = en + pn[e];
    os[t] = inv * (0.5f * S + inv * fmaf(0.5f * inv, U, -W));
  }
}

extern "C" void kernel_launch(void* const* d_in, const int* in_sizes, int n_in,
                              void* d_out, int out_size, void* d_ws, size_t ws_size,
                              hipStream_t stream) {
  const float* k = (const float*)d_in[1];
  const float* v = (const float*)d_in[2];
  float* out = (float*)d_out;
  float* ws = (float*)d_ws;
  float* pref = ws;
  float* kap = ws + (size_t)BB * NCH * 8192;
  float* nu  = kap + BB * LL;
  float* uu  = nu + BB * LL;
  float* ww  = uu + BB * LL;
  hipLaunchKernelGGL(k1_partial, dim3(BB * NCH * 2), dim3(256), 0, stream, k, v, pref, kap, nu);
  hipLaunchKernelGGL(k2_prefix, dim3(BB * 8192 / 256), dim3(256), 0, stream, pref);
  hipLaunchKernelGGL(k3_mfma, dim3(BB * NCH), dim3(512), 0, stream, k, v, pref, uu, ww);
  hipLaunchKernelGGL(k4_out, dim3(BB), dim3(256), 0, stream, uu, ww, nu, out);
}

// Round 9
// 22.944 us; speedup vs baseline: 11.5281x; 1.4556x over previous
//
#include <hip/hip_runtime.h>

#define BB 8
#define LL 2048
#define CC 64
#define NCH 32
#define SB 72   // bf16 LDS row stride (144 B): 16B-aligned, 2-way-free banks

typedef float f32x4 __attribute__((ext_vector_type(4)));
typedef short bf8 __attribute__((ext_vector_type(8)));

static __device__ __forceinline__ unsigned short f2b(float f) {
  unsigned u = __builtin_bit_cast(unsigned, f);
  u += 0x7fff + ((u >> 16) & 1);   // RNE (no NaN in this data)
  return (unsigned short)(u >> 16);
}
static __device__ __forceinline__ float b2f(unsigned short h) {
  return __builtin_bit_cast(float, ((unsigned)h) << 16);
}
#define MFMA(A, B, C) __builtin_amdgcn_mfma_f32_16x16x32_bf16(A, B, C, 0, 0, 0)

// ws layout: pref[BB*NCH*8192 ushort] | nu[BB*LL f32] | u[BB*LL f32] | w[BB*LL f32]

// K1: MFMA per-chunk partials. PA[i][j]=sum_t Vc[t][i]Kc[t][j], PK=Kc^T Kc.
// One block (512 thr) per chunk; operands are the transposed tiles VcT/KcT
// ([out-idx][k=t] layout), exactly the fragment scheme k3 validated.
__global__ __launch_bounds__(512, 4) void k1_mfma(const float* __restrict__ k,
                                                  const float* __restrict__ v,
                                                  unsigned short* __restrict__ pref) {
  __shared__ unsigned short sKcT[64 * SB], sVcT[64 * SB];
  int s = blockIdx.x >> 5, c = blockIdx.x & 31;
  int tid = threadIdx.x;
  int tok0 = s * LL + c * CC;
  const float* kb = k + (size_t)tok0 * 64;
  const float* vb = v + (size_t)tok0 * 64;
  {
    int r = tid >> 3, cb = (tid & 7) * 8;
    f32x4 ka_ = *(const f32x4*)(kb + r * 64 + cb);
    f32x4 kb_ = *(const f32x4*)(kb + r * 64 + cb + 4);
    f32x4 va_ = *(const f32x4*)(vb + r * 64 + cb);
    f32x4 vb_ = *(const f32x4*)(vb + r * 64 + cb + 4);
    #pragma unroll
    for (int u = 0; u < 4; ++u) {
      sKcT[(cb + u) * SB + r] = f2b(ka_[u]);
      sKcT[(cb + 4 + u) * SB + r] = f2b(kb_[u]);
      sVcT[(cb + u) * SB + r] = f2b(va_[u]);
      sVcT[(cb + 4 + u) * SB + r] = f2b(vb_[u]);
    }
  }
  __syncthreads();
  int l = tid & 63, q = tid >> 6;
  int R0 = (q & 3) * 16, C0 = (q >> 2) * 32;
  int ar = R0 + (l & 15);
  int ko = (l >> 4) * 8;
#define LDA(T, ks) (*(const bf8*)&(T)[ar * SB + ko + (ks) * 32])
#define LDB(T, nt, ks) (*(const bf8*)&(T)[(C0 + 16 * (nt) + (l & 15)) * SB + ko + (ks) * 32])
  f32x4 PA[2] = {}, PK[2] = {};
  #pragma unroll
  for (int ks = 0; ks < 2; ++ks) {
    bf8 aV = LDA(sVcT, ks), aK = LDA(sKcT, ks);
    #pragma unroll
    for (int nt = 0; nt < 2; ++nt) {
      bf8 bK = LDB(sKcT, nt, ks);
      PA[nt] = MFMA(aV, bK, PA[nt]);
      PK[nt] = MFMA(aK, bK, PK[nt]);
    }
  }
  unsigned short* dst = pref + (size_t)(s * NCH + c) * 8192;
  #pragma unroll
  for (int nt = 0; nt < 2; ++nt)
    #pragma unroll
    for (int reg = 0; reg < 4; ++reg) {
      int row = R0 + (l >> 4) * 4 + reg;
      int col = C0 + 16 * nt + (l & 15);
      dst[row * 64 + col] = f2b(PA[nt][reg]);
      dst[4096 + row * 64 + col] = f2b(PK[nt][reg]);
    }
#undef LDA
#undef LDB
}

// K2: exclusive prefix over 32 chunks, bf16 in/out, fp32 accumulate.
__global__ __launch_bounds__(256) void k2_prefix(unsigned short* __restrict__ pref) {
  int gid = blockIdx.x * 256 + threadIdx.x;   // [0, BB*8192)
  int s = gid >> 13, e = gid & 8191;
  unsigned short* base = pref + (size_t)s * NCH * 8192 + e;
  unsigned short x[16], y[16];
  #pragma unroll
  for (int u = 0; u < 16; ++u) x[u] = base[(size_t)u * 8192];
  #pragma unroll
  for (int u = 0; u < 16; ++u) y[u] = base[(size_t)(16 + u) * 8192];
  float acc = 0.f;
  #pragma unroll
  for (int u = 0; u < 16; ++u) {
    float t = b2f(x[u]);
    base[(size_t)u * 8192] = f2b(acc);
    acc += t;
  }
  #pragma unroll
  for (int u = 0; u < 16; ++u) {
    float t = b2f(y[u]);
    base[(size_t)(16 + u) * 8192] = f2b(acc);
    acc += t;
  }
}

// K3: MFMA chunk expansion (proven R8 structure; A0/K0 now raw bf16).
// Also emits nu = diag(N) for K4.
__global__ __launch_bounds__(512, 1) void k3_mfma(const float* __restrict__ k,
                                                  const float* __restrict__ v,
                                                  const unsigned short* __restrict__ pref,
                                                  float* __restrict__ uo,
                                                  float* __restrict__ wo,
                                                  float* __restrict__ nuo) {
  __shared__ unsigned short sKc[64 * SB], sVc[64 * SB], sA0[64 * SB],
                            sK0[64 * SB], sKcT[64 * SB], sVcT[64 * SB];
  __shared__ float sdK[64], sdN[64], comb[64][2][2];
  unsigned short* sP = sK0;    // K0 dead after round A (barrier-guarded)
  unsigned short* sY = sVcT;   // VcT dead after round B (barrier-guarded)
  int s = blockIdx.x >> 5, c = blockIdx.x & 31;
  int tid = threadIdx.x;
  int tok0 = s * LL + c * CC;
  const float* kb = k + (size_t)tok0 * 64;
  const float* vb = v + (size_t)tok0 * 64;
  const unsigned short* gA0 = pref + (size_t)(s * NCH + c) * 8192;
  const unsigned short* gK0 = gA0 + 4096;

  // ---- stage: k/v fp32->bf16 (+transposes); A0/K0 raw bf16 copy
  {
    int r = tid >> 3, cb = (tid & 7) * 8;
    f32x4 ka_ = *(const f32x4*)(kb + r * 64 + cb);
    f32x4 kb_ = *(const f32x4*)(kb + r * 64 + cb + 4);
    f32x4 va_ = *(const f32x4*)(vb + r * 64 + cb);
    f32x4 vb_ = *(const f32x4*)(vb + r * 64 + cb + 4);
    bf8 wa = *(const bf8*)&gA0[r * 64 + cb];
    bf8 wq = *(const bf8*)&gK0[r * 64 + cb];
    bf8 wk, wv;
    #pragma unroll
    for (int u = 0; u < 4; ++u) {
      wk[u] = (short)f2b(ka_[u]); wk[4 + u] = (short)f2b(kb_[u]);
      wv[u] = (short)f2b(va_[u]); wv[4 + u] = (short)f2b(vb_[u]);
    }
    *(bf8*)&sKc[r * SB + cb] = wk;
    *(bf8*)&sVc[r * SB + cb] = wv;
    *(bf8*)&sA0[r * SB + cb] = wa;
    *(bf8*)&sK0[r * SB + cb] = wq;
    #pragma unroll
    for (int u = 0; u < 8; ++u) {
      sKcT[(cb + u) * SB + r] = (unsigned short)wk[u];
      sVcT[(cb + u) * SB + r] = (unsigned short)wv[u];
    }
  }
  __syncthreads();

  int l = tid & 63, q = tid >> 6;
  int R0 = (q & 3) * 16, C0 = (q >> 2) * 32, ch = q >> 2;
  int ar = R0 + (l & 15);
  int ko = (l >> 4) * 8;
#define LDA(T, ks) (*(const bf8*)&(T)[ar * SB + ko + (ks) * 32])
#define LDB(T, nt, ks) (*(const bf8*)&(T)[(C0 + 16 * (nt) + (l & 15)) * SB + ko + (ks) * 32])

  f32x4 X[2] = {}, Y[2] = {}, M[2] = {}, N[2] = {};
  #pragma unroll
  for (int ks = 0; ks < 2; ++ks) {
    bf8 aK = LDA(sKc, ks), aV = LDA(sVc, ks);
    #pragma unroll
    for (int nt = 0; nt < 2; ++nt) {
      M[nt] = MFMA(aK, LDB(sKc, nt, ks), M[nt]);
      N[nt] = MFMA(aV, LDB(sVc, nt, ks), N[nt]);
      X[nt] = MFMA(aK, LDB(sA0, nt, ks), X[nt]);
      Y[nt] = MFMA(aK, LDB(sK0, nt, ks), Y[nt]);
    }
  }
  __syncthreads();   // round-A reads of sK0 done before P overwrites it
  #pragma unroll
  for (int nt = 0; nt < 2; ++nt)
    #pragma unroll
    for (int reg = 0; reg < 4; ++reg) {
      int row = R0 + (l >> 4) * 4 + reg;
      int col = C0 + 16 * nt + (l & 15);
      float m = M[nt][reg];
      sP[row * SB + col] = (col < row) ? f2b(m) : (unsigned short)0;
      if (col == row) { sdK[row] = m; sdN[row] = N[nt][reg]; }
    }
  __syncthreads();
  #pragma unroll
  for (int ks = 0; ks < 2; ++ks) {
    bf8 aP = LDA(sP, ks);
    #pragma unroll
    for (int nt = 0; nt < 2; ++nt) {
      X[nt] = MFMA(aP, LDB(sVcT, nt, ks), X[nt]);
      Y[nt] = MFMA(aP, LDB(sKcT, nt, ks), Y[nt]);
    }
  }
  __syncthreads();   // round-B reads of sVcT done before Y overwrites it
  #pragma unroll
  for (int nt = 0; nt < 2; ++nt)
    #pragma unroll
    for (int reg = 0; reg < 4; ++reg) {
      int row = R0 + (l >> 4) * 4 + reg;
      int col = C0 + 16 * nt + (l & 15);
      sY[row * SB + col] = f2b(Y[nt][reg]);
    }
  __syncthreads();
  f32x4 Z[2] = {}, G[2] = {};
  #pragma unroll
  for (int ks = 0; ks < 2; ++ks) {
    bf8 aY = LDA(sY, ks);
    #pragma unroll
    for (int nt = 0; nt < 2; ++nt) {
      Z[nt] = MFMA(aY, LDB(sKc, nt, ks), Z[nt]);
      G[nt] = MFMA(aY, LDB(sA0, nt, ks), G[nt]);
    }
  }
  // ---- epilogue: per-row dots in D-layout (col=l&15, row=(l>>4)*4+reg)
  #pragma unroll
  for (int reg = 0; reg < 4; ++reg) {
    int row = R0 + (l >> 4) * 4 + reg;
    float ka = sdK[row], nv = sdN[row];
    float pu = 0.f, pw = 0.f;
    #pragma unroll
    for (int nt = 0; nt < 2; ++nt) {
      int col = C0 + 16 * nt + (l & 15);
      float x = X[nt][reg], y = Y[nt][reg], n = N[nt][reg];
      float z = Z[nt][reg], g = G[nt][reg];
      float vtl = b2f(sVc[row * SB + col]);
      float ktl = b2f(sKc[row * SB + col]);
      float zn = (col < row) ? z * n : 0.f;
      float vx = vtl * x;
      pu += 2.f * (vtl * g + zn) + x * x + 2.f * ka * vx + nv * (ktl * y);
      pw += vx;
    }
    #pragma unroll
    for (int mm = 1; mm < 16; mm <<= 1) {
      pu += __shfl_xor(pu, mm, 64);
      pw += __shfl_xor(pw, mm, 64);
    }
    if ((l & 15) == 0) { comb[row][ch][0] = pu; comb[row][ch][1] = pw; }
  }
  __syncthreads();
  if (tid < 64) {
    float ka = sdK[tid], nv = sdN[tid];
    float u = comb[tid][0][0] + comb[tid][1][0] + ka * ka * nv;
    float w = 2.f * (comb[tid][0][1] + comb[tid][1][1]) + ka * nv;
    uo[tok0 + tid] = u;
    wo[tok0 + tid] = w;
    nuo[tok0 + tid] = nv;
  }
#undef LDA
#undef LDB
}

// K4 (proven): per-stream inclusive prefixes of u, w, nu -> out.
__global__ __launch_bounds__(256) void k4_out(const float* __restrict__ u,
                                              const float* __restrict__ w,
                                              const float* __restrict__ nu,
                                              float* __restrict__ out) {
  int s = blockIdx.x;
  int tid = threadIdx.x, l = tid & 63, wv = tid >> 6;
  __shared__ float su[4], sw[4], sn[4];
  const float* us = u + s * LL;
  const float* wsp = w + s * LL;
  const float* ns = nu + s * LL;
  float pu[8], pw[8], pn[8];
  int base = tid * 8;
  {
    float ru = 0, rw = 0, rn = 0;
    #pragma unroll
    for (int e = 0; e < 8; ++e) {
      ru += us[base + e]; pu[e] = ru;
      rw += wsp[base + e]; pw[e] = rw;
      rn += ns[base + e]; pn[e] = rn;
    }
  }
  float tu = pu[7], tw = pw[7], tn = pn[7];
  float iu = tu, iw = tw, in_ = tn;
  #pragma unroll
  for (int off = 1; off < 64; off <<= 1) {
    float a = __shfl_up(iu, off, 64);
    float b = __shfl_up(iw, off, 64);
    float c2 = __shfl_up(in_, off, 64);
    if (l >= off) { iu += a; iw += b; in_ += c2; }
  }
  if (l == 63) { su[wv] = iu; sw[wv] = iw; sn[wv] = in_; }
  __syncthreads();
  float bu = 0, bw = 0, bn = 0;
  for (int i2 = 0; i2 < wv; ++i2) { bu += su[i2]; bw += sw[i2]; bn += sn[i2]; }
  float eu = bu + iu - tu, ew = bw + iw - tw, en = bn + in_ - tn;
  float* os = out + s * LL;
  #pragma unroll
  for (int e = 0; e < 8; ++e) {
    int t = base + e;
    float inv = 1.0f / (float)(t + 1);
    float U = eu + pu[e], W = ew + pw[e], S = en + pn[e];
    os[t] = inv * (0.5f * S + inv * fmaf(0.5f * inv, U, -W));
  }
}

extern "C" void kernel_launch(void* const* d_in, const int* in_sizes, int n_in,
                              void* d_out, int out_size, void* d_ws, size_t ws_size,
                              hipStream_t stream) {
  const float* k = (const float*)d_in[1];
  const float* v = (const float*)d_in[2];
  float* out = (float*)d_out;
  float* ws = (float*)d_ws;
  unsigned short* pref = (unsigned short*)ws;            // BB*NCH*8192 ushorts
  float* nu = ws + (size_t)BB * NCH * 4096;              // after pref (in floats)
  float* uu = nu + BB * LL;
  float* ww = uu + BB * LL;
  hipLaunchKernelGGL(k1_mfma, dim3(BB * NCH), dim3(512), 0, stream, k, v, pref);
  hipLaunchKernelGGL(k2_prefix, dim3(BB * 8192 / 256), dim3(256), 0, stream, pref);
  hipLaunchKernelGGL(k3_mfma, dim3(BB * NCH), dim3(512), 0, stream, k, v, pref, uu, ww, nu);
  hipLaunchKernelGGL(k4_out, dim3(BB), dim3(256), 0, stream, uu, ww, nu, out);
}